// Round 7
// baseline (555.549 us; speedup 1.0000x reference)
//
#include <hip/hip_runtime.h>
#include <hip/hip_bf16.h>
#include <float.h>

#define BATCHES 256
#define NPB     512            // nodes per batch
#define NN      (BATCHES*NPB)  // 131072 total nodes
#define KNN     16
#define KP      17
#define DIN     32
#define DH      128
#define DOUT    8
#define BUFS    20             // phase-2 slots (pair-local thr guarantees <=17)
#define REVC    96             // reverse capacity: 2-D kNN in-degree bound 6K=96
#define ROT     41             // part-stagger: 41 = 1 mod 8 -> disjoint banks

// ---------------------------------------------------------------- KNN
// 4 threads/node, each scans a disjoint 128-candidate quarter.
// Bank fix (R6 regression): part p scans with rotation 41p; the quad's
// four concurrent reads then hit disjoint bank groups (41 = 1 mod 8).
// P1: top-17 d2 values via pair bubble (min, v_med3, max) - order-invariant.
// thr: PAIR-local exact 17th-smallest d2 (half-clean max over lane^1).
// P2: collect j with max(d2,0) <= max(thr2,0), rotated order.
// Final: EXPLICIT lex (dc, j) insertion (order-independent) over the pair's
//   two buffers -> identical sorted list on both pair lanes; then one
//   canonical cross-pair half-clean (shfl 2) + minpos + quad-parity emit.
__global__ __launch_bounds__(256) void knn_kernel(
    const float* __restrict__ obs, int* __restrict__ fill, int* __restrict__ rev) {
  __shared__ float4 cand[NPB];                 // {x, y, sq, -}  8 KiB
  __shared__ unsigned short buf[256 * BUFS];   // 10 KiB
  const int b = blockIdx.x >> 3;               // 8 blocks per batch
  const int oct = blockIdx.x & 7;
  const int tid = threadIdx.x;
  const int part = tid & 3;                    // candidate quarter owned
  const int nl = (tid >> 2) + oct * 64;        // local node id

  for (int l = tid; l < NPB; l += 256) {
    const float* orow = obs + ((size_t)b * NPB + l) * DIN;
    const float xx = orow[0], yy = orow[1];
    const float sq = __fadd_rn(__fmul_rn(xx, xx), __fmul_rn(yy, yy));
    cand[l] = make_float4(xx, yy, sq, 0.0f);
  }
  __syncthreads();

  const float4 me = cand[nl];
  const float x = me.x, y = me.y, s = me.z;
  const int jbase = part * 128;

  // ---------- phase 1: top-17 d2 of own 128, 2 candidates per pass
  float dl[KP];
#pragma unroll
  for (int t = 0; t < KP; ++t) dl[t] = FLT_MAX;

  {
    int rot = (ROT * part) & 127;
    for (int jj = 0; jj < 128; jj += 2) {
      const float4 ca = cand[jbase + rot];
      const float4 cb = cand[jbase + ((rot + 1) & 127)];
      rot = (rot + 2) & 127;
      const float dota = __fadd_rn(__fmul_rn(x, ca.x), __fmul_rn(y, ca.y));
      const float d2a  = __fsub_rn(__fadd_rn(s, ca.z), __fmul_rn(2.0f, dota));
      const float dotb = __fadd_rn(__fmul_rn(x, cb.x), __fmul_rn(y, cb.y));
      const float d2b  = __fsub_rn(__fadd_rn(s, cb.z), __fmul_rn(2.0f, dotb));
      float c0 = fminf(d2a, d2b);
      float c1 = fmaxf(d2a, d2b);
#pragma unroll
      for (int t = 0; t < KP; ++t) {
        const float mn = fminf(dl[t], c0);
        float mdv;
        asm("v_med3_f32 %0, %1, %2, %3" : "=v"(mdv) : "v"(dl[t]), "v"(c0), "v"(c1));
        c1 = fmaxf(dl[t], c1);
        dl[t] = mn;
        c0 = mdv;
      }
    }
  }

  // ---------- pair-local threshold: exact 17th-smallest d2 of pair union
  float thr2 = -FLT_MAX;
#pragma unroll
  for (int i = 0; i < KP; ++i) {
    const float ob = __shfl_xor(dl[KP - 1 - i], 1);
    thr2 = fmaxf(thr2, fminf(dl[i], ob));
  }
  const float thr2c = fmaxf(thr2, 0.0f);

  // ---------- phase 2: collect own candidates (rotated order, no sqrt)
  int cnt = 0;
  const int bufbase = tid * BUFS;
  {
    int rot = (ROT * part) & 127;
    for (int jj = 0; jj < 128; ++jj) {
      const int j = jbase + rot;
      rot = (rot + 1) & 127;
      const float4 c = cand[j];
      const float dot = __fadd_rn(__fmul_rn(x, c.x), __fmul_rn(y, c.y));
      const float d2  = __fsub_rn(__fadd_rn(s, c.z), __fmul_rn(2.0f, dot));
      if (fmaxf(d2, 0.0f) <= thr2c && cnt < BUFS) {
        buf[bufbase + cnt] = (unsigned short)j;
        ++cnt;
      }
    }
  }
  __syncthreads();

  // ---------- final: exact lex (dist,idx) top-17 over the PAIR's items.
  // Explicit lex comparisons -> arrival order irrelevant; both pair lanes
  // produce the identical sorted list.
  const int othercnt = __shfl_xor(cnt, 1);
  const int cntE = (tid & 1) ? othercnt : cnt;
  const int cntO = (tid & 1) ? cnt : othercnt;
  const int evenBase = (tid & ~1) * BUFS;
  const int oddBase  = evenBase + BUFS;

  float fd[KP]; int fi[KP];
#pragma unroll
  for (int t = 0; t < KP; ++t) { fd[t] = FLT_MAX; fi[t] = 0x7fffffff; }
  for (int c = 0; c < cntE + cntO; ++c) {
    const int j = (c < cntE) ? buf[evenBase + c] : buf[oddBase + (c - cntE)];
    const float4 pj = cand[j];
    const float dot = __fadd_rn(__fmul_rn(x, pj.x), __fmul_rn(y, pj.y));
    const float d2  = __fsub_rn(__fadd_rn(s, pj.z), __fmul_rn(2.0f, dot));
    const float dc  = sqrtf(fmaxf(d2, 0.0f));
    const bool enter = (dc < fd[KP - 1]) ||
                       (dc == fd[KP - 1] && j < fi[KP - 1]);
    if (enter) {
      bool shp = true;
#pragma unroll
      for (int t = KP - 1; t >= 1; --t) {
        const bool sh = (dc < fd[t - 1]) || (dc == fd[t - 1] && j < fi[t - 1]);
        const float nd = sh ? fd[t - 1] : (shp ? dc : fd[t]);
        const int   ni = sh ? fi[t - 1] : (shp ? j  : fi[t]);
        fd[t] = nd; fi[t] = ni;
        shp = sh;
      }
      if (shp) { fd[0] = dc; fi[0] = j; }
    }
  }

  // ---------- canonical cross-pair merge (sorted inputs; R3-verified form)
  const int phalf = (tid >> 1) & 1;   // which pair within the quad
  float Ad[KP], Bd[KP]; int Ai[KP], Bi[KP];
#pragma unroll
  for (int t = 0; t < KP; ++t) {
    const float o_d = __shfl_xor(fd[t], 2);
    const int   o_i = __shfl_xor(fi[t], 2);
    Ad[t] = phalf ? o_d : fd[t];
    Ai[t] = phalf ? o_i : fi[t];
    Bd[t] = phalf ? fd[t] : o_d;
    Bi[t] = phalf ? fi[t] : o_i;
  }
  float md[KP]; int mi[KP];
#pragma unroll
  for (int i = 0; i < KP; ++i) {
    const float da = Ad[i], db = Bd[KP - 1 - i];
    const int   ia = Ai[i], ib = Bi[KP - 1 - i];
    const bool aless = (da < db) || (da == db && ia < ib);
    md[i] = aless ? da : db;
    mi[i] = aless ? ia : ib;
  }
  int minpos = 0;
#pragma unroll
  for (int i = 1; i < KP; ++i) {
    const bool less = (md[i] < md[minpos]) ||
                      (md[i] == md[minpos] && mi[i] < mi[minpos]);
    minpos = less ? i : minpos;
  }
  // emit edges: quad lanes split slots by (i & 3)
  const int src = b * NPB + nl;
#pragma unroll
  for (int i = 0; i < KP; ++i) {
    if ((i & 3) == part && i != minpos) {
      const int g = b * NPB + mi[i];
      const int slot = atomicAdd(&fill[g], 1);
      if (slot < REVC) rev[(size_t)g * REVC + slot] = src;
    }
  }
}

// ---------------------------------------------------------------- GEMM
// Block computes 32 rows x 128 cols. Thread = 4 rows x 4 cols.
// DINV epilogue (layer 1 only): dinv[row] = rsqrt(indeg+1).
template <int KDIM, bool DINV>
__global__ __launch_bounds__(256) void gemm_kernel(
    const float* __restrict__ X, const float* __restrict__ W,
    float* __restrict__ H, const int* __restrict__ fill,
    float* __restrict__ dinv) {
  __shared__ float ws[32][DH];
  __shared__ float xs[32][32];
  const int tid = threadIdx.x;
  const int tx = tid & 31;
  const int ty = tid >> 5;
  const int rowBase = blockIdx.x * 32;
  float acc[4][4] = {};

  for (int kb = 0; kb < KDIM; kb += 32) {
    for (int l = tid; l < 32 * DH / 4; l += 256) {
      const int kk = l >> 5;
      const int cc = (l & 31) * 4;
      const float4 w4 = *(const float4*)&W[(size_t)(kb + kk) * DH + cc];
      *(float4*)&ws[kk][cc] = w4;
    }
    for (int l = tid; l < 32 * 32 / 4; l += 256) {
      const int rr = l >> 3;
      const int kk = (l & 7) * 4;
      const float4 x4 = *(const float4*)&X[((size_t)rowBase + rr) * KDIM + kb + kk];
      *(float4*)&xs[rr][kk] = x4;
    }
    __syncthreads();
#pragma unroll
    for (int k4 = 0; k4 < 8; ++k4) {
      float4 xr[4];
#pragma unroll
      for (int r = 0; r < 4; ++r)
        xr[r] = *(const float4*)&xs[ty * 4 + r][k4 * 4];
#pragma unroll
      for (int kk = 0; kk < 4; ++kk) {
        const float4 w4 = *(const float4*)&ws[k4 * 4 + kk][tx * 4];
        const float a0 = ((const float*)&xr[0])[kk];
        const float a1 = ((const float*)&xr[1])[kk];
        const float a2 = ((const float*)&xr[2])[kk];
        const float a3 = ((const float*)&xr[3])[kk];
        acc[0][0] += a0 * w4.x; acc[0][1] += a0 * w4.y; acc[0][2] += a0 * w4.z; acc[0][3] += a0 * w4.w;
        acc[1][0] += a1 * w4.x; acc[1][1] += a1 * w4.y; acc[1][2] += a1 * w4.z; acc[1][3] += a1 * w4.w;
        acc[2][0] += a2 * w4.x; acc[2][1] += a2 * w4.y; acc[2][2] += a2 * w4.z; acc[2][3] += a2 * w4.w;
        acc[3][0] += a3 * w4.x; acc[3][1] += a3 * w4.y; acc[3][2] += a3 * w4.z; acc[3][3] += a3 * w4.w;
      }
    }
    __syncthreads();
  }
#pragma unroll
  for (int r = 0; r < 4; ++r) {
    const float4 o = make_float4(acc[r][0], acc[r][1], acc[r][2], acc[r][3]);
    *(float4*)&H[((size_t)rowBase + ty * 4 + r) * DH + tx * 4] = o;
  }
  if (DINV && tid < 32) {
    const int node = rowBase + tid;
    dinv[node] = rsqrtf((float)fill[node] + 1.0f);
  }
}

// ------------------------------------------------------------- aggregate
// One wave per node; lane = (edge-parity half, float4 chunk q).
// HEAD=false: write tanh(agg+bias) to Xout.
// HEAD=true:  fused output head: out[v] = tanh(agg+bias) @ Wout + bout.
template <bool HEAD>
__global__ __launch_bounds__(256) void agg_kernel(
    const float* __restrict__ H, const int* __restrict__ fill,
    const int* __restrict__ rev, const float* __restrict__ dinv,
    const float* __restrict__ bias, const float* __restrict__ Wout,
    const float* __restrict__ bout, float* __restrict__ Xout) {
  const int gtid = blockIdx.x * blockDim.x + threadIdx.x;
  const int v = gtid >> 6;
  if (v >= NN) return;
  const int lane = threadIdx.x & 63;
  const int half = lane >> 5;
  const int q = lane & 31;
  const float dv = dinv[v];

  float4 acc = make_float4(0.f, 0.f, 0.f, 0.f);
  if (half == 0) {                     // self term once
    const float4 hs = *((const float4*)(H + (size_t)v * DH) + q);
    const float w = dv * dv;
    acc.x = hs.x * w; acc.y = hs.y * w; acc.z = hs.z * w; acc.w = hs.w * w;
  }
  const int len0 = fill[v];
  const int len = len0 < REVC ? len0 : REVC;
  const size_t beg = (size_t)v * REVC;
  for (int e = half; e < len; e += 2) {
    const int i = rev[beg + e];
    const float sc = dinv[i] * dv;
    const float4 h4 = *((const float4*)(H + (size_t)i * DH) + q);
    acc.x += h4.x * sc; acc.y += h4.y * sc;
    acc.z += h4.z * sc; acc.w += h4.w * sc;
  }
  // combine halves (both halves end up with the full sum)
  acc.x += __shfl_xor(acc.x, 32);
  acc.y += __shfl_xor(acc.y, 32);
  acc.z += __shfl_xor(acc.z, 32);
  acc.w += __shfl_xor(acc.w, 32);

  const float4 b4 = *((const float4*)bias + q);
  float4 t;
  t.x = tanhf(acc.x + b4.x);
  t.y = tanhf(acc.y + b4.y);
  t.z = tanhf(acc.z + b4.z);
  t.w = tanhf(acc.w + b4.w);

  if (!HEAD) {
    if (half == 0) *((float4*)(Xout + (size_t)v * DH) + q) = t;
  } else {
    // half h computes outs 4h..4h+3: po[oo] = sum_j t[j]*Wout[4q+j][4h+oo]
    const float4 w0 = *(const float4*)&Wout[(4 * q + 0) * DOUT + 4 * half];
    const float4 w1 = *(const float4*)&Wout[(4 * q + 1) * DOUT + 4 * half];
    const float4 w2 = *(const float4*)&Wout[(4 * q + 2) * DOUT + 4 * half];
    const float4 w3 = *(const float4*)&Wout[(4 * q + 3) * DOUT + 4 * half];
    float4 po;
    po.x = t.x * w0.x + t.y * w1.x + t.z * w2.x + t.w * w3.x;
    po.y = t.x * w0.y + t.y * w1.y + t.z * w2.y + t.w * w3.y;
    po.z = t.x * w0.z + t.y * w1.z + t.z * w2.z + t.w * w3.z;
    po.w = t.x * w0.w + t.y * w1.w + t.z * w2.w + t.w * w3.w;
#pragma unroll
    for (int off = 16; off >= 1; off >>= 1) {
      po.x += __shfl_xor(po.x, off);
      po.y += __shfl_xor(po.y, off);
      po.z += __shfl_xor(po.z, off);
      po.w += __shfl_xor(po.w, off);
    }
    if (q == 0) {
      const float4 bo = *(const float4*)&bout[4 * half];
      po.x += bo.x; po.y += bo.y; po.z += bo.z; po.w += bo.w;
      *(float4*)(Xout + (size_t)v * DOUT + 4 * half) = po;
    }
  }
}

// ---------------------------------------------------------------- launch
extern "C" void kernel_launch(void* const* d_in, const int* in_sizes, int n_in,
                              void* d_out, int out_size, void* d_ws, size_t ws_size,
                              hipStream_t stream) {
  const float* obs  = (const float*)d_in[0];
  const float* W1   = (const float*)d_in[1];
  const float* b1   = (const float*)d_in[2];
  const float* W2   = (const float*)d_in[3];
  const float* b2   = (const float*)d_in[4];
  const float* Wout = (const float*)d_in[5];
  const float* bout = (const float*)d_in[6];
  float* out = (float*)d_out;

  char* p = (char*)d_ws;
  auto carve = [&](size_t bytes) {
    void* r = (void*)p;
    p += (bytes + 255) / 256 * 256;
    return r;
  };
  float* h    = (float*)carve((size_t)NN * DH * 4);       // 67 MB
  float* x1   = (float*)carve((size_t)NN * DH * 4);       // 67 MB
  int*   rev  = (int*)carve((size_t)NN * REVC * 4);       // 50 MB
  int*   fill = (int*)carve((size_t)NN * 4);
  float* dinv = (float*)carve((size_t)NN * 4);

  hipMemsetAsync(fill, 0, (size_t)NN * 4, stream);

  // graph build: knn + direct reverse-adjacency scatter
  knn_kernel<<<BATCHES * 8, 256, 0, stream>>>(obs, fill, rev);

  // layer 1: h = obs @ W1 (+ dinv epilogue) ; x1 = tanh(agg + b1)
  gemm_kernel<DIN, true><<<NN / 32, 256, 0, stream>>>(obs, W1, h, fill, dinv);
  agg_kernel<false><<<NN * 64 / 256, 256, 0, stream>>>(
      h, fill, rev, dinv, b1, nullptr, nullptr, x1);

  // layer 2: h = x1 @ W2 ; out = tanh(agg + b2) @ Wout + bout  (fused head)
  gemm_kernel<DH, false><<<NN / 32, 256, 0, stream>>>(x1, W2, h, nullptr, nullptr);
  agg_kernel<true><<<NN * 64 / 256, 256, 0, stream>>>(
      h, fill, rev, dinv, b2, Wout, bout, out);
}

// Round 8
// 467.908 us; speedup vs baseline: 1.1873x; 1.1873x over previous
//
#include <hip/hip_runtime.h>
#include <hip/hip_bf16.h>
#include <float.h>

#define BATCHES 256
#define NPB     512            // nodes per batch
#define NN      (BATCHES*NPB)  // 131072 total nodes
#define KNN     16
#define KP      17
#define DIN     32
#define DH      128
#define DOUT    8
#define BUFS    24             // phase-2 slots (exact pair thr guarantees <=17)
#define REVC    96             // reverse capacity: 2-D kNN in-degree bound 6K=96

// ---------------------------------------------------------------- KNN
// R5 structure (empirical best: 174 us): 2 threads/node over disjoint
// 256-candidate halves.
// P1: top-17 d2 values via pair bubble (min, v_med3, max). Exact arith.
// thr: exact 17th-smallest d2 of the pair union (half-clean max).
// P2: collect j with max(d2,0) <= max(thr2,0)  (== dc <= thr, no sqrt).
// Final: exact lex (dist,idx) top-17 of OWN items (stable ascending-j
// insertion) + R3-verified canonical lane^1 merge + minpos + parity emit.
// Edges scatter directly into fixed-capacity reverse lists.
__global__ __launch_bounds__(256) void knn_kernel(
    const float* __restrict__ obs, int* __restrict__ fill, int* __restrict__ rev) {
  __shared__ float4 cand[NPB];                 // {x, y, sq, -}  8 KiB
  __shared__ unsigned short buf[256 * BUFS];   // 12 KiB
  const int b = blockIdx.x >> 2;               // 4 blocks per batch
  const int quarter = blockIdx.x & 3;
  const int tid = threadIdx.x;
  const int part = tid & 1;
  const int nl = (tid >> 1) + quarter * 128;

  for (int l = tid; l < NPB; l += 256) {
    const float* orow = obs + ((size_t)b * NPB + l) * DIN;
    const float xx = orow[0], yy = orow[1];
    const float sq = __fadd_rn(__fmul_rn(xx, xx), __fmul_rn(yy, yy));
    cand[l] = make_float4(xx, yy, sq, 0.0f);
  }
  __syncthreads();

  const float4 me = cand[nl];
  const float x = me.x, y = me.y, s = me.z;
  const int jbase = part * 256;

  // ---------- phase 1: top-17 d2 values, 2 candidates per bubble pass
  float dl[KP];
#pragma unroll
  for (int t = 0; t < KP; ++t) dl[t] = FLT_MAX;

  for (int jj = 0; jj < 256; jj += 2) {
    const float4 ca = cand[jbase + jj];
    const float4 cb = cand[jbase + jj + 1];
    const float dota = __fadd_rn(__fmul_rn(x, ca.x), __fmul_rn(y, ca.y));
    const float d2a  = __fsub_rn(__fadd_rn(s, ca.z), __fmul_rn(2.0f, dota));
    const float dotb = __fadd_rn(__fmul_rn(x, cb.x), __fmul_rn(y, cb.y));
    const float d2b  = __fsub_rn(__fadd_rn(s, cb.z), __fmul_rn(2.0f, dotb));
    float c0 = fminf(d2a, d2b);
    float c1 = fmaxf(d2a, d2b);
#pragma unroll
    for (int t = 0; t < KP; ++t) {
      const float mn = fminf(dl[t], c0);
      float mdv;
      asm("v_med3_f32 %0, %1, %2, %3" : "=v"(mdv) : "v"(dl[t]), "v"(c0), "v"(c1));
      c1 = fmaxf(dl[t], c1);
      dl[t] = mn;
      c0 = mdv;
    }
  }

  // ---------- threshold: exact 17th-smallest d2 of lane-pair union
  float thr2 = -FLT_MAX;
#pragma unroll
  for (int i = 0; i < KP; ++i) {
    const float ob = __shfl_xor(dl[KP - 1 - i], 1);
    thr2 = fmaxf(thr2, fminf(dl[i], ob));
  }
  const float thr2c = fmaxf(thr2, 0.0f);

  // ---------- phase 2: collect own candidates (no sqrt; order-equivalent)
  int cnt = 0;
  const int bufbase = tid * BUFS;
  for (int jj = 0; jj < 256; ++jj) {
    const int j = jbase + jj;
    const float4 c = cand[j];
    const float dot = __fadd_rn(__fmul_rn(x, c.x), __fmul_rn(y, c.y));
    const float d2  = __fsub_rn(__fadd_rn(s, c.z), __fmul_rn(2.0f, dot));
    if (fmaxf(d2, 0.0f) <= thr2c && cnt < BUFS) {
      buf[bufbase + cnt] = (unsigned short)j;
      ++cnt;
    }
  }

  // ---------- final: exact lex (dist,idx) top-17 of own collected items
  // (ascending-j buffer order + strict-< chain == stable top_k ties)
  float fd[KP]; int fi[KP];
#pragma unroll
  for (int t = 0; t < KP; ++t) { fd[t] = FLT_MAX; fi[t] = 0x7fffffff; }
  for (int c = 0; c < cnt; ++c) {
    const int j = buf[bufbase + c];
    const float4 pj = cand[j];
    const float dot = __fadd_rn(__fmul_rn(x, pj.x), __fmul_rn(y, pj.y));
    const float d2  = __fsub_rn(__fadd_rn(s, pj.z), __fmul_rn(2.0f, dot));
    const float dc  = sqrtf(fmaxf(d2, 0.0f));
    if (dc < fd[KP - 1]) {
      bool shp = true;
#pragma unroll
      for (int t = KP - 1; t >= 1; --t) {
        const bool sh = dc < fd[t - 1];
        const float nd = sh ? fd[t - 1] : (shp ? dc : fd[t]);
        const int   ni = sh ? fi[t - 1] : (shp ? j  : fi[t]);
        fd[t] = nd; fi[t] = ni;
        shp = sh;
      }
      if (shp) { fd[0] = dc; fi[0] = j; }
    }
  }

  // ---------- canonical merge across lane pair (R3-verified)
  float Ad[KP], Bd[KP]; int Ai[KP], Bi[KP];
#pragma unroll
  for (int t = 0; t < KP; ++t) {
    const float o_d = __shfl_xor(fd[t], 1);
    const int   o_i = __shfl_xor(fi[t], 1);
    Ad[t] = part ? o_d : fd[t];
    Ai[t] = part ? o_i : fi[t];
    Bd[t] = part ? fd[t] : o_d;
    Bi[t] = part ? fi[t] : o_i;
  }
  float md[KP]; int mi[KP];
#pragma unroll
  for (int i = 0; i < KP; ++i) {
    const float da = Ad[i], db = Bd[KP - 1 - i];
    const int   ia = Ai[i], ib = Bi[KP - 1 - i];
    const bool aless = (da < db) || (da == db && ia < ib);
    md[i] = aless ? da : db;
    mi[i] = aless ? ia : ib;
  }
  int minpos = 0;
#pragma unroll
  for (int i = 1; i < KP; ++i) {
    const bool less = (md[i] < md[minpos]) ||
                      (md[i] == md[minpos] && mi[i] < mi[minpos]);
    minpos = less ? i : minpos;
  }
  // emit edges: src = this node, dst = neighbor; scatter into rev[dst]
  const int src = b * NPB + nl;
#pragma unroll
  for (int i = 0; i < KP; ++i) {
    if ((i & 1) == part && i != minpos) {
      const int g = b * NPB + mi[i];
      const int slot = atomicAdd(&fill[g], 1);
      if (slot < REVC) rev[(size_t)g * REVC + slot] = src;
    }
  }
}

// ---------------------------------------------------------------- GEMM
// Block computes 64 rows x 128 cols. Thread = 8 rows x 4 cols.
// xs padded to 36 floats/row (144 B): the 8 ty-groups' ds_read_b128 hit
// disjoint bank groups (was 8-way conflict at 128 B stride).
// DINV epilogue (layer 1 only): dinv[row] = rsqrt(indeg+1).
#define XSP 36
template <int KDIM, bool DINV>
__global__ __launch_bounds__(256) void gemm_kernel(
    const float* __restrict__ X, const float* __restrict__ W,
    float* __restrict__ H, const int* __restrict__ fill,
    float* __restrict__ dinv) {
  __shared__ float ws[32][DH];       // 16 KiB: k-chunk of W
  __shared__ float xs[64][XSP];      // 9 KiB: 64 rows x 32 k (padded)
  const int tid = threadIdx.x;
  const int tx = tid & 31;           // col group: cols 4tx..4tx+3
  const int ty = tid >> 5;           // row group: rows 8ty..8ty+7
  const int rowBase = blockIdx.x * 64;
  float acc[8][4] = {};

  for (int kb = 0; kb < KDIM; kb += 32) {
    // stage W chunk (32 x 128)
#pragma unroll
    for (int l = tid; l < 32 * DH / 4; l += 256) {
      const int kk = l >> 5;
      const int cc = (l & 31) * 4;
      const float4 w4 = *(const float4*)&W[(size_t)(kb + kk) * DH + cc];
      *(float4*)&ws[kk][cc] = w4;
    }
    // stage X chunk (64 rows x 32 k)
#pragma unroll
    for (int l = tid; l < 64 * 32 / 4; l += 256) {
      const int rr = l >> 3;
      const int kk = (l & 7) * 4;
      const float4 x4 = *(const float4*)&X[((size_t)rowBase + rr) * KDIM + kb + kk];
      *(float4*)&xs[rr][kk] = x4;
    }
    __syncthreads();
#pragma unroll
    for (int k4 = 0; k4 < 8; ++k4) {
      float4 xr[8];
#pragma unroll
      for (int r = 0; r < 8; ++r)
        xr[r] = *(const float4*)&xs[ty * 8 + r][k4 * 4];
#pragma unroll
      for (int kk = 0; kk < 4; ++kk) {
        const float4 w4 = *(const float4*)&ws[k4 * 4 + kk][tx * 4];
#pragma unroll
        for (int r = 0; r < 8; ++r) {
          const float a = ((const float*)&xr[r])[kk];
          acc[r][0] += a * w4.x; acc[r][1] += a * w4.y;
          acc[r][2] += a * w4.z; acc[r][3] += a * w4.w;
        }
      }
    }
    __syncthreads();
  }
#pragma unroll
  for (int r = 0; r < 8; ++r) {
    const float4 o = make_float4(acc[r][0], acc[r][1], acc[r][2], acc[r][3]);
    *(float4*)&H[((size_t)rowBase + ty * 8 + r) * DH + tx * 4] = o;
  }
  if (DINV && tid < 64) {
    const int node = rowBase + tid;
    dinv[node] = rsqrtf((float)fill[node] + 1.0f);
  }
}

// ------------------------------------------------------------- aggregate
// One wave per node; lane = (edge-parity half, float4 chunk q).
// XCD-bijective block swizzle: each XCD gets a contiguous node range
// (32 whole batches) so the batch's h-panel (256 KB) stays L2-resident.
// HEAD=false: write tanh(agg+bias) to Xout.
// HEAD=true:  fused output head: out[v] = tanh(agg+bias) @ Wout + bout.
template <bool HEAD>
__global__ __launch_bounds__(256) void agg_kernel(
    const float* __restrict__ H, const int* __restrict__ fill,
    const int* __restrict__ rev, const float* __restrict__ dinv,
    const float* __restrict__ bias, const float* __restrict__ Wout,
    const float* __restrict__ bout, float* __restrict__ Xout) {
  const int cpx = gridDim.x >> 3;          // 32768/8: nwg%8==0 -> bijective
  const int work = (blockIdx.x & 7) * cpx + (blockIdx.x >> 3);
  const int gtid = work * blockDim.x + threadIdx.x;
  const int v = gtid >> 6;
  if (v >= NN) return;
  const int lane = threadIdx.x & 63;
  const int half = lane >> 5;
  const int q = lane & 31;
  const float dv = dinv[v];

  float4 acc = make_float4(0.f, 0.f, 0.f, 0.f);
  if (half == 0) {                     // self term once
    const float4 hs = *((const float4*)(H + (size_t)v * DH) + q);
    const float w = dv * dv;
    acc.x = hs.x * w; acc.y = hs.y * w; acc.z = hs.z * w; acc.w = hs.w * w;
  }
  const int len0 = fill[v];
  const int len = len0 < REVC ? len0 : REVC;
  const size_t beg = (size_t)v * REVC;
  for (int e = half; e < len; e += 2) {
    const int i = rev[beg + e];
    const float sc = dinv[i] * dv;
    const float4 h4 = *((const float4*)(H + (size_t)i * DH) + q);
    acc.x += h4.x * sc; acc.y += h4.y * sc;
    acc.z += h4.z * sc; acc.w += h4.w * sc;
  }
  // combine halves (both halves end up with the full sum)
  acc.x += __shfl_xor(acc.x, 32);
  acc.y += __shfl_xor(acc.y, 32);
  acc.z += __shfl_xor(acc.z, 32);
  acc.w += __shfl_xor(acc.w, 32);

  const float4 b4 = *((const float4*)bias + q);
  float4 t;
  t.x = tanhf(acc.x + b4.x);
  t.y = tanhf(acc.y + b4.y);
  t.z = tanhf(acc.z + b4.z);
  t.w = tanhf(acc.w + b4.w);

  if (!HEAD) {
    if (half == 0) *((float4*)(Xout + (size_t)v * DH) + q) = t;
  } else {
    // half h computes outs 4h..4h+3: po[oo] = sum_j t[j]*Wout[4q+j][4h+oo]
    const float4 w0 = *(const float4*)&Wout[(4 * q + 0) * DOUT + 4 * half];
    const float4 w1 = *(const float4*)&Wout[(4 * q + 1) * DOUT + 4 * half];
    const float4 w2 = *(const float4*)&Wout[(4 * q + 2) * DOUT + 4 * half];
    const float4 w3 = *(const float4*)&Wout[(4 * q + 3) * DOUT + 4 * half];
    float4 po;
    po.x = t.x * w0.x + t.y * w1.x + t.z * w2.x + t.w * w3.x;
    po.y = t.x * w0.y + t.y * w1.y + t.z * w2.y + t.w * w3.y;
    po.z = t.x * w0.z + t.y * w1.z + t.z * w2.z + t.w * w3.z;
    po.w = t.x * w0.w + t.y * w1.w + t.z * w2.w + t.w * w3.w;
#pragma unroll
    for (int off = 16; off >= 1; off >>= 1) {
      po.x += __shfl_xor(po.x, off);
      po.y += __shfl_xor(po.y, off);
      po.z += __shfl_xor(po.z, off);
      po.w += __shfl_xor(po.w, off);
    }
    if (q == 0) {
      const float4 bo = *(const float4*)&bout[4 * half];
      po.x += bo.x; po.y += bo.y; po.z += bo.z; po.w += bo.w;
      *(float4*)(Xout + (size_t)v * DOUT + 4 * half) = po;
    }
  }
}

// ---------------------------------------------------------------- launch
extern "C" void kernel_launch(void* const* d_in, const int* in_sizes, int n_in,
                              void* d_out, int out_size, void* d_ws, size_t ws_size,
                              hipStream_t stream) {
  const float* obs  = (const float*)d_in[0];
  const float* W1   = (const float*)d_in[1];
  const float* b1   = (const float*)d_in[2];
  const float* W2   = (const float*)d_in[3];
  const float* b2   = (const float*)d_in[4];
  const float* Wout = (const float*)d_in[5];
  const float* bout = (const float*)d_in[6];
  float* out = (float*)d_out;

  char* p = (char*)d_ws;
  auto carve = [&](size_t bytes) {
    void* r = (void*)p;
    p += (bytes + 255) / 256 * 256;
    return r;
  };
  float* h    = (float*)carve((size_t)NN * DH * 4);       // 67 MB
  float* x1   = (float*)carve((size_t)NN * DH * 4);       // 67 MB
  int*   rev  = (int*)carve((size_t)NN * REVC * 4);       // 50 MB
  int*   fill = (int*)carve((size_t)NN * 4);
  float* dinv = (float*)carve((size_t)NN * 4);

  hipMemsetAsync(fill, 0, (size_t)NN * 4, stream);

  // graph build: knn + direct reverse-adjacency scatter
  knn_kernel<<<BATCHES * 4, 256, 0, stream>>>(obs, fill, rev);

  // layer 1: h = obs @ W1 (+ dinv epilogue) ; x1 = tanh(agg + b1)
  gemm_kernel<DIN, true><<<NN / 64, 256, 0, stream>>>(obs, W1, h, fill, dinv);
  agg_kernel<false><<<NN * 64 / 256, 256, 0, stream>>>(
      h, fill, rev, dinv, b1, nullptr, nullptr, x1);

  // layer 2: h = x1 @ W2 ; out = tanh(agg + b2) @ Wout + bout  (fused head)
  gemm_kernel<DH, false><<<NN / 64, 256, 0, stream>>>(x1, W2, h, nullptr, nullptr);
  agg_kernel<true><<<NN * 64 / 256, 256, 0, stream>>>(
      h, fill, rev, dinv, b2, Wout, bout, out);
}

// Round 9
// 402.054 us; speedup vs baseline: 1.3818x; 1.1638x over previous
//
#include <hip/hip_runtime.h>
#include <hip/hip_bf16.h>
#include <float.h>

#define BATCHES 256
#define NPB     512            // nodes per batch
#define NN      (BATCHES*NPB)  // 131072 total nodes
#define KNN     16
#define KP      17
#define DIN     32
#define DH      128
#define DOUT    8
#define BUFS    24             // phase-2 slots (exact pair thr guarantees <=17+ties)
#define REVC    96             // reverse capacity: 2-D kNN in-degree bound 6K=96

// ---------------------------------------------------------------- KNN
// R5/R8 structure (best: 174 us): 2 threads/node over disjoint halves.
// TIE FIX (R9): phase-2 collects with d2 <= thr2*(1+6e-7) — a provable
// superset of the reference criterion dc <= thr (sqrtf collapses distinct
// d2 onto equal dc; R5-R8's raw d2 compare dropped boundary-tie members).
// The final exact lex (dc,j) chain discards the extras.
__global__ __launch_bounds__(256) void knn_kernel(
    const float* __restrict__ obs, int* __restrict__ fill, int* __restrict__ rev) {
  __shared__ float4 cand[NPB];                 // {x, y, sq, -}  8 KiB
  __shared__ unsigned short buf[256 * BUFS];   // 12 KiB
  const int b = blockIdx.x >> 2;               // 4 blocks per batch
  const int quarter = blockIdx.x & 3;
  const int tid = threadIdx.x;
  const int part = tid & 1;
  const int nl = (tid >> 1) + quarter * 128;

  for (int l = tid; l < NPB; l += 256) {
    const float* orow = obs + ((size_t)b * NPB + l) * DIN;
    const float xx = orow[0], yy = orow[1];
    const float sq = __fadd_rn(__fmul_rn(xx, xx), __fmul_rn(yy, yy));
    cand[l] = make_float4(xx, yy, sq, 0.0f);
  }
  __syncthreads();

  const float4 me = cand[nl];
  const float x = me.x, y = me.y, s = me.z;
  const int jbase = part * 256;

  // ---------- phase 1: top-17 d2 values, 2 candidates per bubble pass
  float dl[KP];
#pragma unroll
  for (int t = 0; t < KP; ++t) dl[t] = FLT_MAX;

  for (int jj = 0; jj < 256; jj += 2) {
    const float4 ca = cand[jbase + jj];
    const float4 cb = cand[jbase + jj + 1];
    const float dota = __fadd_rn(__fmul_rn(x, ca.x), __fmul_rn(y, ca.y));
    const float d2a  = __fsub_rn(__fadd_rn(s, ca.z), __fmul_rn(2.0f, dota));
    const float dotb = __fadd_rn(__fmul_rn(x, cb.x), __fmul_rn(y, cb.y));
    const float d2b  = __fsub_rn(__fadd_rn(s, cb.z), __fmul_rn(2.0f, dotb));
    float c0 = fminf(d2a, d2b);
    float c1 = fmaxf(d2a, d2b);
#pragma unroll
    for (int t = 0; t < KP; ++t) {
      const float mn = fminf(dl[t], c0);
      float mdv;
      asm("v_med3_f32 %0, %1, %2, %3" : "=v"(mdv) : "v"(dl[t]), "v"(c0), "v"(c1));
      c1 = fmaxf(dl[t], c1);
      dl[t] = mn;
      c0 = mdv;
    }
  }

  // ---------- threshold: exact 17th-smallest d2 of lane-pair union
  float thr2 = -FLT_MAX;
#pragma unroll
  for (int i = 0; i < KP; ++i) {
    const float ob = __shfl_xor(dl[KP - 1 - i], 1);
    thr2 = fmaxf(thr2, fminf(dl[i], ob));
  }
  // inflate a few ulps: superset of { d2 : sqrtf(max(d2,0)) <= thr_dc }
  const float thrInf = fmaxf(thr2, 0.0f) * (1.0f + 6e-7f);

  // ---------- phase 2: collect own candidates (superset, ascending j)
  int cnt = 0;
  const int bufbase = tid * BUFS;
  for (int jj = 0; jj < 256; ++jj) {
    const int j = jbase + jj;
    const float4 c = cand[j];
    const float dot = __fadd_rn(__fmul_rn(x, c.x), __fmul_rn(y, c.y));
    const float d2  = __fsub_rn(__fadd_rn(s, c.z), __fmul_rn(2.0f, dot));
    if (d2 <= thrInf && cnt < BUFS) {
      buf[bufbase + cnt] = (unsigned short)j;
      ++cnt;
    }
  }

  // ---------- final: exact lex (dist, idx) top-17 of own collected items
  // (ascending-j arrival + strict-< chain == stable top_k tie semantics)
  float fd[KP]; int fi[KP];
#pragma unroll
  for (int t = 0; t < KP; ++t) { fd[t] = FLT_MAX; fi[t] = 0x7fffffff; }
  for (int c = 0; c < cnt; ++c) {
    const int j = buf[bufbase + c];
    const float4 pj = cand[j];
    const float dot = __fadd_rn(__fmul_rn(x, pj.x), __fmul_rn(y, pj.y));
    const float d2  = __fsub_rn(__fadd_rn(s, pj.z), __fmul_rn(2.0f, dot));
    const float dc  = sqrtf(fmaxf(d2, 0.0f));
    if (dc < fd[KP - 1]) {
      bool shp = true;
#pragma unroll
      for (int t = KP - 1; t >= 1; --t) {
        const bool sh = dc < fd[t - 1];
        const float nd = sh ? fd[t - 1] : (shp ? dc : fd[t]);
        const int   ni = sh ? fi[t - 1] : (shp ? j  : fi[t]);
        fd[t] = nd; fi[t] = ni;
        shp = sh;
      }
      if (shp) { fd[0] = dc; fi[0] = j; }
    }
  }

  // ---------- canonical merge across lane pair (R3-verified)
  float Ad[KP], Bd[KP]; int Ai[KP], Bi[KP];
#pragma unroll
  for (int t = 0; t < KP; ++t) {
    const float o_d = __shfl_xor(fd[t], 1);
    const int   o_i = __shfl_xor(fi[t], 1);
    Ad[t] = part ? o_d : fd[t];
    Ai[t] = part ? o_i : fi[t];
    Bd[t] = part ? fd[t] : o_d;
    Bi[t] = part ? fi[t] : o_i;
  }
  float md[KP]; int mi[KP];
#pragma unroll
  for (int i = 0; i < KP; ++i) {
    const float da = Ad[i], db = Bd[KP - 1 - i];
    const int   ia = Ai[i], ib = Bi[KP - 1 - i];
    const bool aless = (da < db) || (da == db && ia < ib);
    md[i] = aless ? da : db;
    mi[i] = aless ? ia : ib;
  }
  int minpos = 0;
#pragma unroll
  for (int i = 1; i < KP; ++i) {
    const bool less = (md[i] < md[minpos]) ||
                      (md[i] == md[minpos] && mi[i] < mi[minpos]);
    minpos = less ? i : minpos;
  }
  // emit edges: src = this node, dst = neighbor; scatter into rev[dst]
  const int src = b * NPB + nl;
#pragma unroll
  for (int i = 0; i < KP; ++i) {
    if ((i & 1) == part && i != minpos) {
      const int g = b * NPB + mi[i];
      const int slot = atomicAdd(&fill[g], 1);
      if (slot < REVC) rev[(size_t)g * REVC + slot] = src;
    }
  }
}

// ------------------------------------------------------------- dinv
// 1/sqrtf (correctly-rounded divide+sqrt, not rsqrt approx) — restores
// the R4 precision baseline.
__global__ __launch_bounds__(256) void dinv_kernel(
    const int* __restrict__ fill, float* __restrict__ dinv) {
  const int i = blockIdx.x * 256 + threadIdx.x;
  dinv[i] = 1.0f / sqrtf((float)fill[i] + 1.0f);
}

// ---------------------------------------------------- fused GCN layer
// Reassociated: Y = tanh((A_norm . X) @ W + b)   [exact identity with ref]
// Block = 64 nodes, 256 threads.
//  Phase A: 4 threads/node gather-aggregate into LDS xs[64][KDIM(+pad)].
//           Thread p owns float4 columns 4*(p+4c) (bank-disjoint, coalesced
//           64B per quad).
//  Phase B: R8 GEMM (thread = 8 rows x 4 cols) from LDS; tanh+bias.
//  HEAD=false: write 128-dim rows to Y.
//  HEAD=true:  store t to LDS, then out = t @ Wout + bout (2 outs/thread).
template <int KDIM, bool HEAD>
__global__ __launch_bounds__(256) void layer_kernel(
    const float* __restrict__ X, const float* __restrict__ W,
    const float* __restrict__ bias,
    const int* __restrict__ fill, const int* __restrict__ rev,
    const float* __restrict__ dinv,
    const float* __restrict__ Wout, const float* __restrict__ bout,
    float* __restrict__ Y) {
  constexpr int XPAD = (KDIM == 32) ? 36 : 132;   // 16B-aligned rows
  __shared__ float xs[64][XPAD];
  __shared__ float ws[32][DH];
  const int tid = threadIdx.x;
  // XCD-bijective swizzle (gridDim.x % 8 == 0): contiguous node ranges/XCD
  const int cpx = gridDim.x >> 3;
  const int blk = (blockIdx.x & 7) * cpx + (blockIdx.x >> 3);
  const int nodeBase = blk * 64;

  // ---- phase A: aggregate
  {
    const int n = tid >> 2;
    const int p = tid & 3;
    const int v = nodeBase + n;
    const float dv = dinv[v];
    constexpr int NC = KDIM / 16;     // float4s per thread (2 or 8)
    float4 a[NC];
    const float wv = dv * dv;
#pragma unroll
    for (int c = 0; c < NC; ++c) {
      const float4 xv = *((const float4*)(X + (size_t)v * KDIM) + (p + 4 * c));
      a[c].x = xv.x * wv; a[c].y = xv.y * wv;
      a[c].z = xv.z * wv; a[c].w = xv.w * wv;
    }
    const int len0 = fill[v];
    const int len = len0 < REVC ? len0 : REVC;
    const size_t beg = (size_t)v * REVC;
    for (int e = 0; e < len; ++e) {
      const int i = rev[beg + e];
      const float sc = dinv[i] * dv;
#pragma unroll
      for (int c = 0; c < NC; ++c) {
        const float4 xv = *((const float4*)(X + (size_t)i * KDIM) + (p + 4 * c));
        a[c].x += xv.x * sc; a[c].y += xv.y * sc;
        a[c].z += xv.z * sc; a[c].w += xv.w * sc;
      }
    }
#pragma unroll
    for (int c = 0; c < NC; ++c)
      *(float4*)&xs[n][4 * (p + 4 * c)] = a[c];
  }
  __syncthreads();

  // ---- phase B: GEMM (rows = nodes, cols = 128 outputs)
  const int tx = tid & 31;
  const int ty = tid >> 5;
  float acc[8][4] = {};
  for (int kb = 0; kb < KDIM; kb += 32) {
#pragma unroll
    for (int l = tid; l < 32 * DH / 4; l += 256) {
      const int kk = l >> 5;
      const int cc = (l & 31) * 4;
      const float4 w4 = *(const float4*)&W[(size_t)(kb + kk) * DH + cc];
      *(float4*)&ws[kk][cc] = w4;
    }
    __syncthreads();
#pragma unroll
    for (int k4 = 0; k4 < 8; ++k4) {
      float4 xr[8];
#pragma unroll
      for (int r = 0; r < 8; ++r)
        xr[r] = *(const float4*)&xs[ty * 8 + r][kb + k4 * 4];
#pragma unroll
      for (int kk = 0; kk < 4; ++kk) {
        const float4 w4 = *(const float4*)&ws[k4 * 4 + kk][tx * 4];
#pragma unroll
        for (int r = 0; r < 8; ++r) {
          const float a = ((const float*)&xr[r])[kk];
          acc[r][0] += a * w4.x; acc[r][1] += a * w4.y;
          acc[r][2] += a * w4.z; acc[r][3] += a * w4.w;
        }
      }
    }
    __syncthreads();
  }
  const float4 b4 = *(const float4*)&bias[tx * 4];
  float4 t[8];
#pragma unroll
  for (int r = 0; r < 8; ++r) {
    t[r].x = tanhf(acc[r][0] + b4.x);
    t[r].y = tanhf(acc[r][1] + b4.y);
    t[r].z = tanhf(acc[r][2] + b4.z);
    t[r].w = tanhf(acc[r][3] + b4.w);
  }

  if (!HEAD) {
#pragma unroll
    for (int r = 0; r < 8; ++r)
      *(float4*)&Y[((size_t)nodeBase + ty * 8 + r) * DH + tx * 4] = t[r];
  } else {
    // stash t into xs (all reads of xs are done: post-loop barrier above)
#pragma unroll
    for (int r = 0; r < 8; ++r)
      *(float4*)&xs[ty * 8 + r][tx * 4] = t[r];
    __syncthreads();
    // head: thread -> node tid>>2, outs {2p, 2p+1}
    const int n = tid >> 2;
    const int p = tid & 3;
    float2 po = make_float2(0.0f, 0.0f);
#pragma unroll 8
    for (int c4 = 0; c4 < 32; ++c4) {
      const float4 xv = *(const float4*)&xs[n][c4 * 4];
      const float2 w0 = *(const float2*)&Wout[(c4 * 4 + 0) * DOUT + 2 * p];
      const float2 w1 = *(const float2*)&Wout[(c4 * 4 + 1) * DOUT + 2 * p];
      const float2 w2 = *(const float2*)&Wout[(c4 * 4 + 2) * DOUT + 2 * p];
      const float2 w3 = *(const float2*)&Wout[(c4 * 4 + 3) * DOUT + 2 * p];
      po.x += xv.x * w0.x + xv.y * w1.x + xv.z * w2.x + xv.w * w3.x;
      po.y += xv.x * w0.y + xv.y * w1.y + xv.z * w2.y + xv.w * w3.y;
    }
    const float2 bo = *(const float2*)&bout[2 * p];
    po.x += bo.x; po.y += bo.y;
    *(float2*)&Y[(size_t)(nodeBase + n) * DOUT + 2 * p] = po;
  }
}

// ---------------------------------------------------------------- launch
extern "C" void kernel_launch(void* const* d_in, const int* in_sizes, int n_in,
                              void* d_out, int out_size, void* d_ws, size_t ws_size,
                              hipStream_t stream) {
  const float* obs  = (const float*)d_in[0];
  const float* W1   = (const float*)d_in[1];
  const float* b1   = (const float*)d_in[2];
  const float* W2   = (const float*)d_in[3];
  const float* b2   = (const float*)d_in[4];
  const float* Wout = (const float*)d_in[5];
  const float* bout = (const float*)d_in[6];
  float* out = (float*)d_out;

  char* p = (char*)d_ws;
  auto carve = [&](size_t bytes) {
    void* r = (void*)p;
    p += (bytes + 255) / 256 * 256;
    return r;
  };
  float* x1   = (float*)carve((size_t)NN * DH * 4);       // 67 MB
  int*   rev  = (int*)carve((size_t)NN * REVC * 4);       // 50 MB
  int*   fill = (int*)carve((size_t)NN * 4);
  float* dinv = (float*)carve((size_t)NN * 4);

  hipMemsetAsync(fill, 0, (size_t)NN * 4, stream);

  // graph build: knn + direct reverse-adjacency scatter, then degrees
  knn_kernel<<<BATCHES * 4, 256, 0, stream>>>(obs, fill, rev);
  dinv_kernel<<<NN / 256, 256, 0, stream>>>(fill, dinv);

  // layer 1 (reassociated, fused): x1 = tanh((A.obs) @ W1 + b1)
  layer_kernel<DIN, false><<<NN / 64, 256, 0, stream>>>(
      obs, W1, b1, fill, rev, dinv, nullptr, nullptr, x1);

  // layer 2 + head (fused): out = tanh((A.x1) @ W2 + b2) @ Wout + bout
  layer_kernel<DH, true><<<NN / 64, 256, 0, stream>>>(
      x1, W2, b2, fill, rev, dinv, Wout, bout, out);
}

// Round 10
// 390.354 us; speedup vs baseline: 1.4232x; 1.0300x over previous
//
#include <hip/hip_runtime.h>
#include <hip/hip_bf16.h>
#include <float.h>

#define BATCHES 256
#define NPB     512            // nodes per batch
#define NN      (BATCHES*NPB)  // 131072 total nodes
#define KNN     16
#define KP      17
#define DIN     32
#define DH      128
#define DOUT    8
#define BUFS    24             // phase-2 slots (exact pair thr + slack <= ~20)
#define REVC    96             // reverse capacity: 2-D kNN in-degree bound 6K=96

// ---------------------------------------------------------------- KNN
// 2 threads/node over disjoint 256-candidate halves (R5/R8 structure).
// R10: phases 1-2 use FAST-FMA d2 (3 ops vs 6) on LDS-(−2x,−2y,sq);
// scaling by −2 / recovery by −0.5 are exact (power of 2), so the final
// chain recomputes the reference-exact d2 bit-identically. The fast
// threshold is inflated by an absolute 1e-3 (≥ 2x the fma-vs-exact error
// bound ~2e-5) -> provable superset; exact lex (dc,j) final chain +
// R3-verified canonical merge give reference-identical selection.
__global__ __launch_bounds__(256) void knn_kernel(
    const float* __restrict__ obs, int* __restrict__ fill, int* __restrict__ rev) {
  __shared__ float4 cand[NPB];                 // {-2x, -2y, sq, -}  8 KiB
  __shared__ unsigned short buf[256 * BUFS];   // 12 KiB
  const int b = blockIdx.x >> 2;               // 4 blocks per batch
  const int quarter = blockIdx.x & 3;
  const int tid = threadIdx.x;
  const int part = tid & 1;
  const int nl = (tid >> 1) + quarter * 128;

  for (int l = tid; l < NPB; l += 256) {
    const float* orow = obs + ((size_t)b * NPB + l) * DIN;
    const float xx = orow[0], yy = orow[1];
    const float sq = __fadd_rn(__fmul_rn(xx, xx), __fmul_rn(yy, yy));
    cand[l] = make_float4(-2.0f * xx, -2.0f * yy, sq, 0.0f);
  }
  __syncthreads();

  const float4 me = cand[nl];
  const float x = -0.5f * me.x;   // exact recovery
  const float y = -0.5f * me.y;
  const float s = me.z;
  const int jbase = part * 256;

  // ---------- phase 1: top-17 fast-d2 values, 2 candidates per pass
  float dl[KP];
#pragma unroll
  for (int t = 0; t < KP; ++t) dl[t] = FLT_MAX;

  for (int jj = 0; jj < 256; jj += 2) {
    const float4 ca = cand[jbase + jj];
    const float4 cb = cand[jbase + jj + 1];
    const float d2a = __fadd_rn(__fmaf_rn(ca.x, x, __fmaf_rn(ca.y, y, ca.z)), s);
    const float d2b = __fadd_rn(__fmaf_rn(cb.x, x, __fmaf_rn(cb.y, y, cb.z)), s);
    float c0 = fminf(d2a, d2b);
    float c1 = fmaxf(d2a, d2b);
#pragma unroll
    for (int t = 0; t < KP; ++t) {
      const float mn = fminf(dl[t], c0);
      float mdv;
      asm("v_med3_f32 %0, %1, %2, %3" : "=v"(mdv) : "v"(dl[t]), "v"(c0), "v"(c1));
      c1 = fmaxf(dl[t], c1);
      dl[t] = mn;
      c0 = mdv;
    }
  }

  // ---------- threshold: 17th-smallest fast-d2 of lane-pair union
  float thr2 = -FLT_MAX;
#pragma unroll
  for (int i = 0; i < KP; ++i) {
    const float ob = __shfl_xor(dl[KP - 1 - i], 1);
    thr2 = fmaxf(thr2, fminf(dl[i], ob));
  }
  const float thrInf = thr2 + 1e-3f;   // absolute slack >= 2x fma error bound

  // ---------- phase 2: collect own candidates (fast d2, superset)
  int cnt = 0;
  const int bufbase = tid * BUFS;
#pragma unroll 2
  for (int jj = 0; jj < 256; ++jj) {
    const int j = jbase + jj;
    const float4 c = cand[j];
    const float d2 = __fadd_rn(__fmaf_rn(c.x, x, __fmaf_rn(c.y, y, c.z)), s);
    if (d2 <= thrInf && cnt < BUFS) {
      buf[bufbase + cnt] = (unsigned short)j;
      ++cnt;
    }
  }

  // ---------- final: exact lex (dist, idx) top-17 of own collected items
  // (reference-exact arithmetic; ascending-j arrival + strict-< chain ==
  //  stable top_k tie semantics)
  float fd[KP]; int fi[KP];
#pragma unroll
  for (int t = 0; t < KP; ++t) { fd[t] = FLT_MAX; fi[t] = 0x7fffffff; }
  for (int c = 0; c < cnt; ++c) {
    const int j = buf[bufbase + c];
    const float4 pj = cand[j];
    const float px = -0.5f * pj.x;   // exact
    const float py = -0.5f * pj.y;
    const float dot = __fadd_rn(__fmul_rn(x, px), __fmul_rn(y, py));
    const float d2  = __fsub_rn(__fadd_rn(s, pj.z), __fmul_rn(2.0f, dot));
    const float dc  = sqrtf(fmaxf(d2, 0.0f));
    if (dc < fd[KP - 1]) {
      bool shp = true;
#pragma unroll
      for (int t = KP - 1; t >= 1; --t) {
        const bool sh = dc < fd[t - 1];
        const float nd = sh ? fd[t - 1] : (shp ? dc : fd[t]);
        const int   ni = sh ? fi[t - 1] : (shp ? j  : fi[t]);
        fd[t] = nd; fi[t] = ni;
        shp = sh;
      }
      if (shp) { fd[0] = dc; fi[0] = j; }
    }
  }

  // ---------- canonical merge across lane pair (R3-verified)
  float Ad[KP], Bd[KP]; int Ai[KP], Bi[KP];
#pragma unroll
  for (int t = 0; t < KP; ++t) {
    const float o_d = __shfl_xor(fd[t], 1);
    const int   o_i = __shfl_xor(fi[t], 1);
    Ad[t] = part ? o_d : fd[t];
    Ai[t] = part ? o_i : fi[t];
    Bd[t] = part ? fd[t] : o_d;
    Bi[t] = part ? fi[t] : o_i;
  }
  float md[KP]; int mi[KP];
#pragma unroll
  for (int i = 0; i < KP; ++i) {
    const float da = Ad[i], db = Bd[KP - 1 - i];
    const int   ia = Ai[i], ib = Bi[KP - 1 - i];
    const bool aless = (da < db) || (da == db && ia < ib);
    md[i] = aless ? da : db;
    mi[i] = aless ? ia : ib;
  }
  int minpos = 0;
#pragma unroll
  for (int i = 1; i < KP; ++i) {
    const bool less = (md[i] < md[minpos]) ||
                      (md[i] == md[minpos] && mi[i] < mi[minpos]);
    minpos = less ? i : minpos;
  }
  // emit edges: src = this node, dst = neighbor; scatter into rev[dst]
  const int src = b * NPB + nl;
#pragma unroll
  for (int i = 0; i < KP; ++i) {
    if ((i & 1) == part && i != minpos) {
      const int g = b * NPB + mi[i];
      const int slot = atomicAdd(&fill[g], 1);
      if (slot < REVC) rev[(size_t)g * REVC + slot] = src;
    }
  }
}

// ------------------------------------------------------------- dinv
__global__ __launch_bounds__(256) void dinv_kernel(
    const int* __restrict__ fill, float* __restrict__ dinv) {
  const int i = blockIdx.x * 256 + threadIdx.x;
  dinv[i] = 1.0f / sqrtf((float)fill[i] + 1.0f);
}

// ---------------------------------------------------- fused GCN layer
// Reassociated: Y = tanh((A_norm . X) @ W + b)   [exact identity with ref]
// Block = 64 nodes, 256 threads.
//  Phase A: 4 threads/node gather-aggregate into LDS xs.
//  Phase B: GEMM (thread = 8 rows x 4 cols) from LDS, W staged in
//           8-k chunks (ws 4 KB) -> layer2 LDS 37.8 KB = 4 blocks/CU.
//  HEAD=true: out = tanh(.) @ Wout + bout fused.
template <int KDIM, bool HEAD>
__global__ __launch_bounds__(256) void layer_kernel(
    const float* __restrict__ X, const float* __restrict__ W,
    const float* __restrict__ bias,
    const int* __restrict__ fill, const int* __restrict__ rev,
    const float* __restrict__ dinv,
    const float* __restrict__ Wout, const float* __restrict__ bout,
    float* __restrict__ Y) {
  constexpr int XPAD = (KDIM == 32) ? 36 : 132;   // 16B-aligned rows
  __shared__ float xs[64][XPAD];
  __shared__ float ws[8][DH];       // 4 KiB W chunk
  const int tid = threadIdx.x;
  // XCD-bijective swizzle (gridDim.x % 8 == 0): contiguous node ranges/XCD
  const int cpx = gridDim.x >> 3;
  const int blk = (blockIdx.x & 7) * cpx + (blockIdx.x >> 3);
  const int nodeBase = blk * 64;

  // ---- phase A: aggregate
  {
    const int n = tid >> 2;
    const int p = tid & 3;
    const int v = nodeBase + n;
    const float dv = dinv[v];
    constexpr int NC = KDIM / 16;     // float4s per thread (2 or 8)
    float4 a[NC];
    const float wv = dv * dv;
#pragma unroll
    for (int c = 0; c < NC; ++c) {
      const float4 xv = *((const float4*)(X + (size_t)v * KDIM) + (p + 4 * c));
      a[c].x = xv.x * wv; a[c].y = xv.y * wv;
      a[c].z = xv.z * wv; a[c].w = xv.w * wv;
    }
    const int len0 = fill[v];
    const int len = len0 < REVC ? len0 : REVC;
    const size_t beg = (size_t)v * REVC;
    for (int e = 0; e < len; ++e) {
      const int i = rev[beg + e];
      const float sc = dinv[i] * dv;
#pragma unroll
      for (int c = 0; c < NC; ++c) {
        const float4 xv = *((const float4*)(X + (size_t)i * KDIM) + (p + 4 * c));
        a[c].x += xv.x * sc; a[c].y += xv.y * sc;
        a[c].z += xv.z * sc; a[c].w += xv.w * sc;
      }
    }
#pragma unroll
    for (int c = 0; c < NC; ++c)
      *(float4*)&xs[n][4 * (p + 4 * c)] = a[c];
  }
  __syncthreads();

  // ---- phase B: GEMM (rows = nodes, cols = 128 outputs), 8-k chunks
  const int tx = tid & 31;
  const int ty = tid >> 5;
  float acc[8][4] = {};
  for (int kb = 0; kb < KDIM; kb += 8) {
    {
      // stage 8x128 W chunk: 256 float4s, 1 per thread, coalesced
      const int kk = tid >> 5;
      const int cc = (tid & 31) * 4;
      *(float4*)&ws[kk][cc] = *(const float4*)&W[(size_t)(kb + kk) * DH + cc];
    }
    __syncthreads();
#pragma unroll
    for (int k4 = 0; k4 < 2; ++k4) {
      float4 xr[8];
#pragma unroll
      for (int r = 0; r < 8; ++r)
        xr[r] = *(const float4*)&xs[ty * 8 + r][kb + k4 * 4];
#pragma unroll
      for (int kk = 0; kk < 4; ++kk) {
        const float4 w4 = *(const float4*)&ws[k4 * 4 + kk][tx * 4];
#pragma unroll
        for (int r = 0; r < 8; ++r) {
          const float a = ((const float*)&xr[r])[kk];
          acc[r][0] += a * w4.x; acc[r][1] += a * w4.y;
          acc[r][2] += a * w4.z; acc[r][3] += a * w4.w;
        }
      }
    }
    __syncthreads();
  }
  const float4 b4 = *(const float4*)&bias[tx * 4];
  float4 t[8];
#pragma unroll
  for (int r = 0; r < 8; ++r) {
    t[r].x = tanhf(acc[r][0] + b4.x);
    t[r].y = tanhf(acc[r][1] + b4.y);
    t[r].z = tanhf(acc[r][2] + b4.z);
    t[r].w = tanhf(acc[r][3] + b4.w);
  }

  if (!HEAD) {
#pragma unroll
    for (int r = 0; r < 8; ++r)
      *(float4*)&Y[((size_t)nodeBase + ty * 8 + r) * DH + tx * 4] = t[r];
  } else {
    // stash t into xs (last chunk's trailing barrier above ended all reads)
#pragma unroll
    for (int r = 0; r < 8; ++r)
      *(float4*)&xs[ty * 8 + r][tx * 4] = t[r];
    __syncthreads();
    // head: thread -> node tid>>2, outs {2p, 2p+1}
    const int n = tid >> 2;
    const int p = tid & 3;
    float2 po = make_float2(0.0f, 0.0f);
#pragma unroll 8
    for (int c4 = 0; c4 < 32; ++c4) {
      const float4 xv = *(const float4*)&xs[n][c4 * 4];
      const float2 w0 = *(const float2*)&Wout[(c4 * 4 + 0) * DOUT + 2 * p];
      const float2 w1 = *(const float2*)&Wout[(c4 * 4 + 1) * DOUT + 2 * p];
      const float2 w2 = *(const float2*)&Wout[(c4 * 4 + 2) * DOUT + 2 * p];
      const float2 w3 = *(const float2*)&Wout[(c4 * 4 + 3) * DOUT + 2 * p];
      po.x += xv.x * w0.x + xv.y * w1.x + xv.z * w2.x + xv.w * w3.x;
      po.y += xv.x * w0.y + xv.y * w1.y + xv.z * w2.y + xv.w * w3.y;
    }
    const float2 bo = *(const float2*)&bout[2 * p];
    po.x += bo.x; po.y += bo.y;
    *(float2*)&Y[(size_t)(nodeBase + n) * DOUT + 2 * p] = po;
  }
}

// ---------------------------------------------------------------- launch
extern "C" void kernel_launch(void* const* d_in, const int* in_sizes, int n_in,
                              void* d_out, int out_size, void* d_ws, size_t ws_size,
                              hipStream_t stream) {
  const float* obs  = (const float*)d_in[0];
  const float* W1   = (const float*)d_in[1];
  const float* b1   = (const float*)d_in[2];
  const float* W2   = (const float*)d_in[3];
  const float* b2   = (const float*)d_in[4];
  const float* Wout = (const float*)d_in[5];
  const float* bout = (const float*)d_in[6];
  float* out = (float*)d_out;

  char* p = (char*)d_ws;
  auto carve = [&](size_t bytes) {
    void* r = (void*)p;
    p += (bytes + 255) / 256 * 256;
    return r;
  };
  float* x1   = (float*)carve((size_t)NN * DH * 4);       // 67 MB
  int*   rev  = (int*)carve((size_t)NN * REVC * 4);       // 50 MB
  int*   fill = (int*)carve((size_t)NN * 4);
  float* dinv = (float*)carve((size_t)NN * 4);

  hipMemsetAsync(fill, 0, (size_t)NN * 4, stream);

  // graph build: knn + direct reverse-adjacency scatter, then degrees
  knn_kernel<<<BATCHES * 4, 256, 0, stream>>>(obs, fill, rev);
  dinv_kernel<<<NN / 256, 256, 0, stream>>>(fill, dinv);

  // layer 1 (reassociated, fused): x1 = tanh((A.obs) @ W1 + b1)
  layer_kernel<DIN, false><<<NN / 64, 256, 0, stream>>>(
      obs, W1, b1, fill, rev, dinv, nullptr, nullptr, x1);

  // layer 2 + head (fused): out = tanh((A.x1) @ W2 + b2) @ Wout + bout
  layer_kernel<DH, true><<<NN / 64, 256, 0, stream>>>(
      x1, W2, b2, fill, rev, dinv, Wout, bout, out);
}

// Round 11
// 370.200 us; speedup vs baseline: 1.5007x; 1.0544x over previous
//
#include <hip/hip_runtime.h>
#include <hip/hip_bf16.h>
#include <float.h>

#define BATCHES 256
#define NPB     512            // nodes per batch
#define NN      (BATCHES*NPB)  // 131072 total nodes
#define KNN     16
#define KP      17
#define DIN     32
#define DH      128
#define DOUT    8
#define BUFS    24             // phase-2 slots (exact pair thr + slack <= ~20)
#define REVC    96             // reverse capacity: 2-D kNN in-degree bound 6K=96

// ---------------------------------------------------------------- KNN
// 2 threads/node over disjoint 256-candidate halves (R5/R8 structure).
// R11: phase 1 inserts FOUR sorted candidates per bubble pass.
// With carries c0<=c1<=c2<=c3 and d=dl[t], the drop-min/keep-4-sorted
// update is: dl[t]=min(d,c0); c0'=med3(d,c0,c1); c1'=med3(d,c1,c2);
// c2'=med3(d,c2,c3); c3'=max(d,c3).   (case-verified for all 5 ranks of d)
// -> 26.75 ops/candidate (was 29.5) and HALF the serial med3 chain depth.
// Phases 1-2 use fast-fma d2 on (-2x,-2y,sq) (R10, exact-recoverable);
// threshold inflated +1e-3 -> provable superset; final chain is
// reference-exact lex (dc,j) -> selection identical to jax.lax.top_k.
__global__ __launch_bounds__(256) void knn_kernel(
    const float* __restrict__ obs, int* __restrict__ fill, int* __restrict__ rev) {
  __shared__ float4 cand[NPB];                 // {-2x, -2y, sq, -}  8 KiB
  __shared__ unsigned short buf[256 * BUFS];   // 12 KiB
  const int b = blockIdx.x >> 2;               // 4 blocks per batch
  const int quarter = blockIdx.x & 3;
  const int tid = threadIdx.x;
  const int part = tid & 1;
  const int nl = (tid >> 1) + quarter * 128;

  for (int l = tid; l < NPB; l += 256) {
    const float* orow = obs + ((size_t)b * NPB + l) * DIN;
    const float xx = orow[0], yy = orow[1];
    const float sq = __fadd_rn(__fmul_rn(xx, xx), __fmul_rn(yy, yy));
    cand[l] = make_float4(-2.0f * xx, -2.0f * yy, sq, 0.0f);
  }
  __syncthreads();

  const float4 me = cand[nl];
  const float x = -0.5f * me.x;   // exact recovery
  const float y = -0.5f * me.y;
  const float s = me.z;
  const int jbase = part * 256;

  // ---------- phase 1: top-17 fast-d2 values, 4 candidates per pass
  float dl[KP];
#pragma unroll
  for (int t = 0; t < KP; ++t) dl[t] = FLT_MAX;

  for (int jj = 0; jj < 256; jj += 4) {
    const float4 cA = cand[jbase + jj];
    const float4 cB = cand[jbase + jj + 1];
    const float4 cC = cand[jbase + jj + 2];
    const float4 cD = cand[jbase + jj + 3];
    const float dA = __fadd_rn(__fmaf_rn(cA.x, x, __fmaf_rn(cA.y, y, cA.z)), s);
    const float dB = __fadd_rn(__fmaf_rn(cB.x, x, __fmaf_rn(cB.y, y, cB.z)), s);
    const float dC = __fadd_rn(__fmaf_rn(cC.x, x, __fmaf_rn(cC.y, y, cC.z)), s);
    const float dD = __fadd_rn(__fmaf_rn(cD.x, x, __fmaf_rn(cD.y, y, cD.z)), s);
    // sort-4 network: (0,1)(2,3)(0,2)(1,3)(1,2)
    const float t0 = fminf(dA, dB), t1 = fmaxf(dA, dB);
    const float t2 = fminf(dC, dD), t3 = fmaxf(dC, dD);
    float c0 = fminf(t0, t2);
    const float u1 = fmaxf(t0, t2);
    float c3 = fmaxf(t1, t3);
    const float u2 = fminf(t1, t3);
    float c1 = fminf(u1, u2);
    float c2 = fmaxf(u1, u2);
#pragma unroll
    for (int t = 0; t < KP; ++t) {
      const float d = dl[t];
      const float mn = fminf(d, c0);
      float m0, m1, m2;
      asm("v_med3_f32 %0, %1, %2, %3" : "=v"(m0) : "v"(d), "v"(c0), "v"(c1));
      asm("v_med3_f32 %0, %1, %2, %3" : "=v"(m1) : "v"(d), "v"(c1), "v"(c2));
      asm("v_med3_f32 %0, %1, %2, %3" : "=v"(m2) : "v"(d), "v"(c2), "v"(c3));
      const float mx = fmaxf(d, c3);
      dl[t] = mn;
      c0 = m0; c1 = m1; c2 = m2; c3 = mx;
    }
  }

  // ---------- threshold: 17th-smallest fast-d2 of lane-pair union
  float thr2 = -FLT_MAX;
#pragma unroll
  for (int i = 0; i < KP; ++i) {
    const float ob = __shfl_xor(dl[KP - 1 - i], 1);
    thr2 = fmaxf(thr2, fminf(dl[i], ob));
  }
  const float thrInf = thr2 + 1e-3f;   // absolute slack >= 2x fma error bound

  // ---------- phase 2: collect own candidates (fast d2, superset)
  int cnt = 0;
  const int bufbase = tid * BUFS;
#pragma unroll 2
  for (int jj = 0; jj < 256; ++jj) {
    const int j = jbase + jj;
    const float4 c = cand[j];
    const float d2 = __fadd_rn(__fmaf_rn(c.x, x, __fmaf_rn(c.y, y, c.z)), s);
    if (d2 <= thrInf && cnt < BUFS) {
      buf[bufbase + cnt] = (unsigned short)j;
      ++cnt;
    }
  }

  // ---------- final: exact lex (dist, idx) top-17 of own collected items
  // (reference-exact arithmetic; ascending-j arrival + strict-< chain ==
  //  stable top_k tie semantics)
  float fd[KP]; int fi[KP];
#pragma unroll
  for (int t = 0; t < KP; ++t) { fd[t] = FLT_MAX; fi[t] = 0x7fffffff; }
  for (int c = 0; c < cnt; ++c) {
    const int j = buf[bufbase + c];
    const float4 pj = cand[j];
    const float px = -0.5f * pj.x;   // exact
    const float py = -0.5f * pj.y;
    const float dot = __fadd_rn(__fmul_rn(x, px), __fmul_rn(y, py));
    const float d2  = __fsub_rn(__fadd_rn(s, pj.z), __fmul_rn(2.0f, dot));
    const float dc  = sqrtf(fmaxf(d2, 0.0f));
    if (dc < fd[KP - 1]) {
      bool shp = true;
#pragma unroll
      for (int t = KP - 1; t >= 1; --t) {
        const bool sh = dc < fd[t - 1];
        const float nd = sh ? fd[t - 1] : (shp ? dc : fd[t]);
        const int   ni = sh ? fi[t - 1] : (shp ? j  : fi[t]);
        fd[t] = nd; fi[t] = ni;
        shp = sh;
      }
      if (shp) { fd[0] = dc; fi[0] = j; }
    }
  }

  // ---------- canonical merge across lane pair (R3-verified)
  float Ad[KP], Bd[KP]; int Ai[KP], Bi[KP];
#pragma unroll
  for (int t = 0; t < KP; ++t) {
    const float o_d = __shfl_xor(fd[t], 1);
    const int   o_i = __shfl_xor(fi[t], 1);
    Ad[t] = part ? o_d : fd[t];
    Ai[t] = part ? o_i : fi[t];
    Bd[t] = part ? fd[t] : o_d;
    Bi[t] = part ? fi[t] : o_i;
  }
  float md[KP]; int mi[KP];
#pragma unroll
  for (int i = 0; i < KP; ++i) {
    const float da = Ad[i], db = Bd[KP - 1 - i];
    const int   ia = Ai[i], ib = Bi[KP - 1 - i];
    const bool aless = (da < db) || (da == db && ia < ib);
    md[i] = aless ? da : db;
    mi[i] = aless ? ia : ib;
  }
  int minpos = 0;
#pragma unroll
  for (int i = 1; i < KP; ++i) {
    const bool less = (md[i] < md[minpos]) ||
                      (md[i] == md[minpos] && mi[i] < mi[minpos]);
    minpos = less ? i : minpos;
  }
  // emit edges: src = this node, dst = neighbor; scatter into rev[dst]
  const int src = b * NPB + nl;
#pragma unroll
  for (int i = 0; i < KP; ++i) {
    if ((i & 1) == part && i != minpos) {
      const int g = b * NPB + mi[i];
      const int slot = atomicAdd(&fill[g], 1);
      if (slot < REVC) rev[(size_t)g * REVC + slot] = src;
    }
  }
}

// ------------------------------------------------------------- dinv
__global__ __launch_bounds__(256) void dinv_kernel(
    const int* __restrict__ fill, float* __restrict__ dinv) {
  const int i = blockIdx.x * 256 + threadIdx.x;
  dinv[i] = 1.0f / sqrtf((float)fill[i] + 1.0f);
}

// ---------------------------------------------------- fused GCN layer
// Reassociated: Y = tanh((A_norm . X) @ W + b)   [exact identity with ref]
// Block = 64 nodes, 256 threads.
//  Phase A: 4 threads/node gather-aggregate into LDS xs.
//  Phase B: GEMM (thread = 8 rows x 4 cols) from LDS, W staged in
//           8-k chunks (ws 4 KB) -> layer2 LDS 37.8 KB = 4 blocks/CU.
//  HEAD=true: out = tanh(.) @ Wout + bout fused.
template <int KDIM, bool HEAD>
__global__ __launch_bounds__(256) void layer_kernel(
    const float* __restrict__ X, const float* __restrict__ W,
    const float* __restrict__ bias,
    const int* __restrict__ fill, const int* __restrict__ rev,
    const float* __restrict__ dinv,
    const float* __restrict__ Wout, const float* __restrict__ bout,
    float* __restrict__ Y) {
  constexpr int XPAD = (KDIM == 32) ? 36 : 132;   // 16B-aligned rows
  __shared__ float xs[64][XPAD];
  __shared__ float ws[8][DH];       // 4 KiB W chunk
  const int tid = threadIdx.x;
  // XCD-bijective swizzle (gridDim.x % 8 == 0): contiguous node ranges/XCD
  const int cpx = gridDim.x >> 3;
  const int blk = (blockIdx.x & 7) * cpx + (blockIdx.x >> 3);
  const int nodeBase = blk * 64;

  // ---- phase A: aggregate
  {
    const int n = tid >> 2;
    const int p = tid & 3;
    const int v = nodeBase + n;
    const float dv = dinv[v];
    constexpr int NC = KDIM / 16;     // float4s per thread (2 or 8)
    float4 a[NC];
    const float wv = dv * dv;
#pragma unroll
    for (int c = 0; c < NC; ++c) {
      const float4 xv = *((const float4*)(X + (size_t)v * KDIM) + (p + 4 * c));
      a[c].x = xv.x * wv; a[c].y = xv.y * wv;
      a[c].z = xv.z * wv; a[c].w = xv.w * wv;
    }
    const int len0 = fill[v];
    const int len = len0 < REVC ? len0 : REVC;
    const size_t beg = (size_t)v * REVC;
    for (int e = 0; e < len; ++e) {
      const int i = rev[beg + e];
      const float sc = dinv[i] * dv;
#pragma unroll
      for (int c = 0; c < NC; ++c) {
        const float4 xv = *((const float4*)(X + (size_t)i * KDIM) + (p + 4 * c));
        a[c].x += xv.x * sc; a[c].y += xv.y * sc;
        a[c].z += xv.z * sc; a[c].w += xv.w * sc;
      }
    }
#pragma unroll
    for (int c = 0; c < NC; ++c)
      *(float4*)&xs[n][4 * (p + 4 * c)] = a[c];
  }
  __syncthreads();

  // ---- phase B: GEMM (rows = nodes, cols = 128 outputs), 8-k chunks
  const int tx = tid & 31;
  const int ty = tid >> 5;
  float acc[8][4] = {};
  for (int kb = 0; kb < KDIM; kb += 8) {
    {
      // stage 8x128 W chunk: 256 float4s, 1 per thread, coalesced
      const int kk = tid >> 5;
      const int cc = (tid & 31) * 4;
      *(float4*)&ws[kk][cc] = *(const float4*)&W[(size_t)(kb + kk) * DH + cc];
    }
    __syncthreads();
#pragma unroll
    for (int k4 = 0; k4 < 2; ++k4) {
      float4 xr[8];
#pragma unroll
      for (int r = 0; r < 8; ++r)
        xr[r] = *(const float4*)&xs[ty * 8 + r][kb + k4 * 4];
#pragma unroll
      for (int kk = 0; kk < 4; ++kk) {
        const float4 w4 = *(const float4*)&ws[k4 * 4 + kk][tx * 4];
#pragma unroll
        for (int r = 0; r < 8; ++r) {
          const float a = ((const float*)&xr[r])[kk];
          acc[r][0] += a * w4.x; acc[r][1] += a * w4.y;
          acc[r][2] += a * w4.z; acc[r][3] += a * w4.w;
        }
      }
    }
    __syncthreads();
  }
  const float4 b4 = *(const float4*)&bias[tx * 4];
  float4 t[8];
#pragma unroll
  for (int r = 0; r < 8; ++r) {
    t[r].x = tanhf(acc[r][0] + b4.x);
    t[r].y = tanhf(acc[r][1] + b4.y);
    t[r].z = tanhf(acc[r][2] + b4.z);
    t[r].w = tanhf(acc[r][3] + b4.w);
  }

  if (!HEAD) {
#pragma unroll
    for (int r = 0; r < 8; ++r)
      *(float4*)&Y[((size_t)nodeBase + ty * 8 + r) * DH + tx * 4] = t[r];
  } else {
    // stash t into xs (last chunk's trailing barrier above ended all reads)
#pragma unroll
    for (int r = 0; r < 8; ++r)
      *(float4*)&xs[ty * 8 + r][tx * 4] = t[r];
    __syncthreads();
    // head: thread -> node tid>>2, outs {2p, 2p+1}
    const int n = tid >> 2;
    const int p = tid & 3;
    float2 po = make_float2(0.0f, 0.0f);
#pragma unroll 8
    for (int c4 = 0; c4 < 32; ++c4) {
      const float4 xv = *(const float4*)&xs[n][c4 * 4];
      const float2 w0 = *(const float2*)&Wout[(c4 * 4 + 0) * DOUT + 2 * p];
      const float2 w1 = *(const float2*)&Wout[(c4 * 4 + 1) * DOUT + 2 * p];
      const float2 w2 = *(const float2*)&Wout[(c4 * 4 + 2) * DOUT + 2 * p];
      const float2 w3 = *(const float2*)&Wout[(c4 * 4 + 3) * DOUT + 2 * p];
      po.x += xv.x * w0.x + xv.y * w1.x + xv.z * w2.x + xv.w * w3.x;
      po.y += xv.x * w0.y + xv.y * w1.y + xv.z * w2.y + xv.w * w3.y;
    }
    const float2 bo = *(const float2*)&bout[2 * p];
    po.x += bo.x; po.y += bo.y;
    *(float2*)&Y[(size_t)(nodeBase + n) * DOUT + 2 * p] = po;
  }
}

// ---------------------------------------------------------------- launch
extern "C" void kernel_launch(void* const* d_in, const int* in_sizes, int n_in,
                              void* d_out, int out_size, void* d_ws, size_t ws_size,
                              hipStream_t stream) {
  const float* obs  = (const float*)d_in[0];
  const float* W1   = (const float*)d_in[1];
  const float* b1   = (const float*)d_in[2];
  const float* W2   = (const float*)d_in[3];
  const float* b2   = (const float*)d_in[4];
  const float* Wout = (const float*)d_in[5];
  const float* bout = (const float*)d_in[6];
  float* out = (float*)d_out;

  char* p = (char*)d_ws;
  auto carve = [&](size_t bytes) {
    void* r = (void*)p;
    p += (bytes + 255) / 256 * 256;
    return r;
  };
  float* x1   = (float*)carve((size_t)NN * DH * 4);       // 67 MB
  int*   rev  = (int*)carve((size_t)NN * REVC * 4);       // 50 MB
  int*   fill = (int*)carve((size_t)NN * 4);
  float* dinv = (float*)carve((size_t)NN * 4);

  hipMemsetAsync(fill, 0, (size_t)NN * 4, stream);

  // graph build: knn + direct reverse-adjacency scatter, then degrees
  knn_kernel<<<BATCHES * 4, 256, 0, stream>>>(obs, fill, rev);
  dinv_kernel<<<NN / 256, 256, 0, stream>>>(fill, dinv);

  // layer 1 (reassociated, fused): x1 = tanh((A.obs) @ W1 + b1)
  layer_kernel<DIN, false><<<NN / 64, 256, 0, stream>>>(
      obs, W1, b1, fill, rev, dinv, nullptr, nullptr, x1);

  // layer 2 + head (fused): out = tanh((A.x1) @ W2 + b2) @ Wout + bout
  layer_kernel<DH, true><<<NN / 64, 256, 0, stream>>>(
      x1, W2, b2, fill, rev, dinv, Wout, bout, out);
}